// Round 10
// baseline (264.844 us; speedup 1.0000x reference)
//
#include <hip/hip_runtime.h>

typedef unsigned short u16;
typedef unsigned int   u32;
typedef int      i32x4  __attribute__((ext_vector_type(4)));
typedef float    f32x4  __attribute__((ext_vector_type(4)));

// Problem constants
#define LHW   53
#define NP    2809
#define KDIM  3072
#define NMEM  8192
#define PADW  84
#define IMG   64
#define MPAD  2816           // 22 * 128 zero-padded patch rows
#define BIGF  3.402823466e+38f
#define MARGIN 24.0f         // i8-screen margin in D units (~17 sigma of pairwise err)
#define QS    31.75f         // i8 scale = 127/4
#define C2    (2.0f / (QS * QS))
#define CAP   12             // candidate slots per (patch, 64-col split)

// ---------------- fast-path ws layout (byte offsets, 256-aligned) ----------
#define O_XP    0UL           // 21168 f32
#define O_MSQ   84736UL       // 8192 f32
#define O_MI8   117504UL      // 8192*3072 i8
#define O_AI8   25283328UL    // 2816*3072 i8
#define O_CANDD 33934080UL    // NP*128*CAP f32
#define O_CANDJ 51192576UL    // NP*128*CAP i32
#define O_CNT   68451072UL    // NP*128 i32
#define O_ROWI  69889280UL    // NP i32
#define O_PART  69900544UL    // 53*3*32*84 f32 partial rows
#define O_ACC   71610112UL    // 12288 f32
#define WS_NEED4 71659264UL

// ---------------- legacy (fallback) ws layout (float-unit offsets) ---------
#define F_XP    0
#define F_MSQ   21504
#define F_PVAL  29696
#define F_PIDX  119584
#define F_ROW   209472
#define F_ACC   212288
#define F_MAX   224576
#define NSPL    32
#define NRANGE  (NMEM / NSPL)

__device__ inline char q8(float x) {
    float y = x * QS;
    y = fminf(fmaxf(y, -127.f), 127.f);
    return (char)__float2int_rn(y);
}

// ============================ shared small kernels ==========================
__global__ void k_xp(const float* __restrict__ image, float* __restrict__ xp) {
    int id = blockIdx.x * 256 + threadIdx.x;
    if (id < 3 * PADW * PADW) {
        int c = id / (PADW * PADW), rem = id % (PADW * PADW);
        int py = rem / PADW, px = rem % PADW;
        float v = 0.f;
        if (py >= 10 && py < 74 && px >= 10 && px < 74)
            v = image[((py - 10) * IMG + (px - 10)) * 3 + c];
        xp[id] = v;
    }
}

// fused max + normalize, single block
__global__ __launch_bounds__(1024) void k_maxnorm(const float* __restrict__ acc,
                                                  float* __restrict__ out) {
    int t = threadIdx.x;
    float m = -BIGF;
    for (int i = t; i < 12288; i += 1024) m = fmaxf(m, acc[i]);
    #pragma unroll
    for (int s = 1; s < 64; s <<= 1) m = fmaxf(m, __shfl_xor(m, s));
    __shared__ float ls[16];
    int lane = t & 63, w = t >> 6;
    if (lane == 0) ls[w] = m;
    __syncthreads();
    float mv = ls[0];
    #pragma unroll
    for (int i = 1; i < 16; ++i) mv = fmaxf(mv, ls[i]);
    for (int i = t; i < 12288; i += 1024) {
        int c = i >> 12, y = (i >> 6) & 63, x = i & 63;
        out[(y * IMG + x) * 3 + c] = acc[i] / mv;
    }
}

// ============================== fast path ===================================
// mem -> i8 plane + exact f32 row sq-norms in one pass
__global__ __launch_bounds__(256) void k_quantmsq(const float* __restrict__ mem,
                                                  char* __restrict__ mq,
                                                  float* __restrict__ msq) {
    int j = blockIdx.x, t = threadIdx.x;
    const float4* r4 = (const float4*)(mem + (size_t)j * KDIM);
    char4* q4 = (char4*)(mq + (size_t)j * KDIM);
    float s = 0.f;
    #pragma unroll
    for (int i = 0; i < 3; ++i) {
        int idx = i * 256 + t;
        float4 v = r4[idx];
        s += v.x * v.x + v.y * v.y + v.z * v.z + v.w * v.w;
        char4 q = {q8(v.x), q8(v.y), q8(v.z), q8(v.w)};
        q4[idx] = q;
    }
    #pragma unroll
    for (int m = 1; m < 64; m <<= 1) s += __shfl_xor(s, m);
    __shared__ float ls[4];
    int lane = t & 63, w = t >> 6;
    if (lane == 0) ls[w] = s;
    __syncthreads();
    if (t == 0) msq[j] = ls[0] + ls[1] + ls[2] + ls[3];
}

// patch matrix (MPAD x KDIM) i8, rows >= NP zero; 4 elems/thread.
// Also zeros the candidate counters (runs before the GEMM in-stream).
__global__ __launch_bounds__(256) void k_quant_A(const float* __restrict__ xp,
                                                 char* __restrict__ aq,
                                                 int* __restrict__ cnt) {
    int id = blockIdx.x * 256 + threadIdx.x;      // over char4: 2816*3072/4
    if (id < NP * 128) cnt[id] = 0;
    int e0 = id * 4;
    int p = e0 / KDIM, k = e0 - p * KDIM;
    char4 q = {0, 0, 0, 0};
    if (p < NP) {
        int c = k >> 10, kh = (k >> 5) & 31, kw = k & 31;
        int lh = p / LHW, lw = p - lh * LHW;
        const float* src = xp + c * (PADW * PADW) + (lh + kh) * PADW + lw + kw;
        q.x = q8(src[0]); q.y = q8(src[1]); q.z = q8(src[2]); q.w = q8(src[3]);
    }
    ((char4*)aq)[id] = q;
}

// i8 screening MFMA GEMM with in-epilogue candidate collection.
// 128x128 tile, BK=128 (i8), 4 waves of 64x64. Staging: global_load_lds with
// pre-swizzled global source, linear LDS dest (verified round 8/9 layout),
// double-buffered. Epilogue: per (patch row, 64-col split) store (d, j) pairs
// with d <= split_min + MARGIN (superset of global-threshold candidates,
// since split_min >= global_min). CAP=12 overflow P ~ 1e-11/split.
__global__ __launch_bounds__(256) void k_gemm_i8(
    const char* __restrict__ Aq, const char* __restrict__ Bq,
    const float* __restrict__ msq, float* __restrict__ candd,
    int* __restrict__ candj, int* __restrict__ cnt)
{
    __shared__ __align__(16) char lds[65536];   // buf0/buf1: A @0, B @16384
    const int t = threadIdx.x;
    const int lane = t & 63;
    const int w = t >> 6, wm = w >> 1, wn = w & 1;
    const int mrow = lane & 15;

    // XCD-chunked bijective swizzle: 1408 = 8 * 176
    int L = blockIdx.x;
    int logical = (L & 7) * 176 + (L >> 3);
    int by = logical / 22, bx = logical - by * 22;
    const int rowBase = bx * 128;     // patch rows (A)
    const int jBase   = by * 128;     // mem rows (B)

    // slot s: plane P=s>>2 (A/B), sub=s&3; this wave covers rows sub*32+w*8..+7
    const int lrow = lane >> 3;             // 0..7
    const int gsrc = (lane & 7) ^ lrow;     // pre-swizzled 16B source group
    const char* gpl[8];
    unsigned ldsb[8];
    #pragma unroll
    for (int s = 0; s < 8; ++s) {
        int P = s >> 2, sub = s & 3;
        int row = sub * 32 + w * 8 + lrow;
        const char* basep = (P == 0 ? Aq : Bq);
        int gRow = (P == 0 ? rowBase : jBase) + row;
        gpl[s]  = basep + (size_t)gRow * KDIM + gsrc * 16;
        ldsb[s] = P * 16384 + (unsigned)(sub * 32 + w * 8) * 128;  // +lane*16 by HW
    }

    i32x4 acc[4][4];
    #pragma unroll
    for (int i = 0; i < 4; ++i)
        #pragma unroll
        for (int j = 0; j < 4; ++j) { i32x4 z = {0, 0, 0, 0}; acc[i][j] = z; }

    // prologue: stage k-chunk 0 into buf0
    #pragma unroll
    for (int s = 0; s < 8; ++s)
        __builtin_amdgcn_global_load_lds(
            (const __attribute__((address_space(1))) void*)(gpl[s]),
            (__attribute__((address_space(3))) void*)(lds + ldsb[s]),
            16, 0, 0);

    for (int kc = 0; kc < 24; ++kc) {
        const int cb = kc & 1;
        __syncthreads();                       // vmcnt drain: buf[cb] ready
        if (kc < 23) {
            const unsigned nb = (cb ^ 1) * 32768u;
            #pragma unroll
            for (int s = 0; s < 8; ++s)
                __builtin_amdgcn_global_load_lds(
                    (const __attribute__((address_space(1))) void*)(gpl[s] + (kc + 1) * 128),
                    (__attribute__((address_space(3))) void*)(lds + nb + ldsb[s]),
                    16, 0, 0);
        }
        const char* lbase = lds + cb * 32768;
        #pragma unroll
        for (int kh2 = 0; kh2 < 2; ++kh2) {
            const int grp = kh2 * 4 + (lane >> 4);
            i32x4 ah[4];
            #pragma unroll
            for (int f = 0; f < 4; ++f) {
                int ra = wm * 64 + f * 16 + mrow;
                ah[f] = *(const i32x4*)(lbase + ra * 128 + (grp ^ (ra & 7)) * 16);
            }
            #pragma unroll
            for (int fj = 0; fj < 4; ++fj) {
                int rb = wn * 64 + fj * 16 + mrow;
                i32x4 bh = *(const i32x4*)(lbase + 16384 + rb * 128 + (grp ^ (rb & 7)) * 16);
                #pragma unroll
                for (int fi = 0; fi < 4; ++fi)
                    acc[fi][fj] = __builtin_amdgcn_mfma_i32_16x16x64_i8(ah[fi], bh, acc[fi][fj], 0, 0, 0);
            }
        }
    }

    // epilogue: d = msq[j]-3072 - 2*dot_q/QS^2; store (d,j) with d<=rowmin+MARGIN
    float ms[4];
    #pragma unroll
    for (int fj = 0; fj < 4; ++fj) ms[fj] = msq[jBase + wn * 64 + fj * 16 + mrow] - 3072.0f;
    const int splitId = by * 2 + wn;
    #pragma unroll
    for (int fi = 0; fi < 4; ++fi) {
        #pragma unroll
        for (int r = 0; r < 4; ++r) {
            int p = rowBase + wm * 64 + fi * 16 + (lane >> 4) * 4 + r;
            float d4[4]; float bv = BIGF;
            #pragma unroll
            for (int fj = 0; fj < 4; ++fj) {
                d4[fj] = fmaf(-C2, (float)acc[fi][fj][r], ms[fj]);
                bv = fminf(bv, d4[fj]);
            }
            #pragma unroll
            for (int m = 1; m < 16; m <<= 1) bv = fminf(bv, __shfl_xor(bv, m));
            if (p < NP) {
                float th = bv + MARGIN;
                int* cp = cnt + (size_t)p * 128 + splitId;
                #pragma unroll
                for (int fj = 0; fj < 4; ++fj) {
                    if (d4[fj] <= th) {
                        int slot = atomicAdd(cp, 1);
                        if (slot < CAP) {
                            size_t off = ((size_t)p * 128 + splitId) * CAP + slot;
                            candd[off] = d4[fj];
                            candj[off] = jBase + wn * 64 + fj * 16 + mrow;
                        }
                    }
                }
            }
        }
    }
}

// per-patch: global min over stored candidates -> threshold -> exact f32 re-eval
__global__ __launch_bounds__(256) void k_refine(
    const float* __restrict__ candd, const int* __restrict__ candj,
    const int* __restrict__ cnt, const float* __restrict__ msq,
    const float* __restrict__ xp, const float* __restrict__ mem,
    const int* __restrict__ mapping, int* __restrict__ rowIdx)
{
    const int p = blockIdx.x, t = threadIdx.x;
    const int lane = t & 63, w = t >> 6;
    __shared__ float wred[4];
    __shared__ int lcnt;
    __shared__ int list[256];
    __shared__ float thr_s;

    // this thread's split (t < 128)
    int n = 0;
    if (t < 128) n = min(cnt[(size_t)p * 128 + t], CAP);
    const float* dp = candd + ((size_t)p * 128 + t) * CAP;
    const int*   jp = candj + ((size_t)p * 128 + t) * CAP;

    // pass 1: global min of stored d (every split's min is stored)
    float gm = BIGF;
    for (int i = 0; i < n; ++i) gm = fminf(gm, dp[i]);
    #pragma unroll
    for (int m = 1; m < 64; m <<= 1) gm = fminf(gm, __shfl_xor(gm, m));
    if (lane == 0) wred[w] = gm;
    if (t == 0) lcnt = 0;
    __syncthreads();
    if (t == 0) thr_s = fminf(fminf(wred[0], wred[1]), fminf(wred[2], wred[3])) + MARGIN;
    __syncthreads();
    const float th = thr_s;

    // pass 2: gather qualifying candidate indices
    for (int i = 0; i < n; ++i)
        if (dp[i] <= th) {
            int sl = atomicAdd(&lcnt, 1);
            if (sl < 256) list[sl] = jp[i];
        }
    __syncthreads();
    int nc = min(lcnt, 256);

    // pass 3: exact f32 evaluation of each candidate (verified logic)
    const int lh = p / LHW, lw = p - (p / LHW) * LHW;
    float bd = BIGF; int bj = 0x7fffffff;
    __shared__ float tot;
    for (int ci = 0; ci < nc; ++ci) {
        int j = list[ci];
        const float* mrow2 = mem + (size_t)j * KDIM;
        float s = 0.f;
        for (int k = t; k < KDIM; k += 256) {
            int c = k >> 10, kh = (k >> 5) & 31, kw = k & 31;
            s += xp[c * (PADW * PADW) + (lh + kh) * PADW + lw + kw] * mrow2[k];
        }
        #pragma unroll
        for (int m = 1; m < 64; m <<= 1) s += __shfl_xor(s, m);
        if (lane == 0) wred[w] = s;
        __syncthreads();
        if (t == 0) tot = wred[0] + wred[1] + wred[2] + wred[3];
        __syncthreads();
        float d = msq[j] - 2.f * tot;
        if (d < bd || (d == bd && j < bj)) { bd = d; bj = j; }
    }
    if (t == 0) rowIdx[p] = mapping[bj];
}

// -------------------- overlap-add: per-(lh,c) scatter into LDS --------------
// Race-free (verified rounds 5-9): __syncthreads() per lw iteration.
__global__ __launch_bounds__(256) void k_scatter(const float* __restrict__ mem2,
                                                 const int* __restrict__ rowIdx,
                                                 float* __restrict__ partial) {
    const int lh = blockIdx.x / 3, c = blockIdx.x % 3;
    __shared__ float accs[32 * 85];
    __shared__ int r2s[53];
    const int t = threadIdx.x;
    for (int i = t; i < 32 * 85; i += 256) accs[i] = 0.f;
    if (t < 53) r2s[t] = rowIdx[lh * LHW + t];
    __syncthreads();
    const int kh  = t >> 3;            // 0..31 (rows disjoint across threads)
    const int kwb = (t & 7) * 4;       // 0,4,...,28
    const size_t coff = (size_t)c * 1024 + kh * 32 + kwb;
    float* a0 = accs + kh * 85 + kwb;
    for (int lw = 0; lw < 53; ++lw) {
        const float4 v = *(const float4*)(mem2 + (size_t)r2s[lw] * KDIM + coff);
        float* a = a0 + lw;
        a[0] += v.x; a[1] += v.y; a[2] += v.z; a[3] += v.w;
        __syncthreads();               // order iterations: no cross-lw RMW race
    }
    float* pbase = partial + ((size_t)(lh * 3 + c)) * 32 * 84;
    for (int i = t; i < 32 * 84; i += 256) {
        int kh2 = i / 84, px = i - kh2 * 84;
        pbase[i] = accs[kh2 * 85 + px];
    }
}

// per-output-pixel reduce over <=32 kh partial rows
__global__ void k_oadd(const float* __restrict__ partial, float* __restrict__ accb) {
    int id = blockIdx.x * 256 + threadIdx.x;   // 12288
    if (id >= 12288) return;
    int c = id >> 12, y = (id >> 6) & 63, x = id & 63;
    int py = y + 10, px = x + 10;
    int khmin = max(0, py - 52), khmax = min(31, py);
    float s = 0.f;
    for (int kh = khmin; kh <= khmax; ++kh) {
        int lh = py - kh;
        s += partial[((lh * 3 + c) * 32 + kh) * 84 + px];
    }
    accb[id] = s;
}

// ======================= legacy f32 pipeline (fallback) =====================
__global__ __launch_bounds__(256) void k_msq(const float* __restrict__ mem,
                                             float* __restrict__ msq) {
    int j = blockIdx.x;
    const float* row = mem + (size_t)j * KDIM;
    float s = 0.f;
    for (int i = threadIdx.x; i < KDIM; i += 256) { float v = row[i]; s += v * v; }
    #pragma unroll
    for (int m = 1; m < 64; m <<= 1) s += __shfl_xor(s, m);
    __shared__ float ls[4];
    int lane = threadIdx.x & 63, w = threadIdx.x >> 6;
    if (lane == 0) ls[w] = s;
    __syncthreads();
    if (threadIdx.x == 0) msq[j] = ls[0] + ls[1] + ls[2] + ls[3];
}

__global__ void k_amin(const float* __restrict__ pval, const int* __restrict__ pidx,
                       const int* __restrict__ mapping, int* __restrict__ rowIdx,
                       int nspl) {
    int p = blockIdx.x * 256 + threadIdx.x;
    if (p < NP) {
        float bv = BIGF; int bi = 0x7fffffff;
        for (int ns = 0; ns < nspl; ++ns) {
            float v = pval[(size_t)p * nspl + ns];
            int ix = pidx[(size_t)p * nspl + ns];
            if (v < bv || (v == bv && ix < bi)) { bv = v; bi = ix; }
        }
        rowIdx[p] = mapping[bi];
    }
}

__global__ __launch_bounds__(256) void k_gather(const float* __restrict__ mem2,
                                                const int* __restrict__ rowIdx,
                                                float* __restrict__ acc) {
    int b = blockIdx.x;
    int c = b >> 12, y = (b >> 6) & 63, x = b & 63;
    int khmin = max(0, y - 42), khmax = min(31, y + 10);
    int kwmin = max(0, x - 42), kwmax = min(31, x + 10);
    int nh = khmax - khmin + 1, nw = kwmax - kwmin + 1;
    int total = nh * nw;
    float s = 0.f;
    for (int idx = threadIdx.x; idx < total; idx += 256) {
        int kh = khmin + idx / nw;
        int kw = kwmin + idx % nw;
        int lh = y + 10 - kh, lw = x + 10 - kw;
        int p = lh * LHW + lw;
        int r2 = rowIdx[p];
        s += mem2[(size_t)r2 * KDIM + c * 1024 + kh * 32 + kw];
    }
    #pragma unroll
    for (int m = 1; m < 64; m <<= 1) s += __shfl_xor(s, m);
    __shared__ float ls[4];
    int lane = threadIdx.x & 63, w = threadIdx.x >> 6;
    if (lane == 0) ls[w] = s;
    __syncthreads();
    if (threadIdx.x == 0) acc[b] = ls[0] + ls[1] + ls[2] + ls[3];
}

__global__ __launch_bounds__(256) void k_gemm_argmin(
    const float* __restrict__ xp, const float* __restrict__ mem,
    const float* __restrict__ msq, float* __restrict__ pval,
    int* __restrict__ pidx)
{
    __shared__ float At[64][33];
    __shared__ float Bt[64][33];
    const int t = threadIdx.x;
    const int tx = t & 15, ty = t >> 4;
    const int rowBase = blockIdx.x * 64;
    const int nBase = blockIdx.y * NRANGE;

    float best[4]; int bidx[4];
    #pragma unroll
    for (int i = 0; i < 4; ++i) { best[i] = BIGF; bidx[i] = 0x7fffffff; }

    for (int nt = 0; nt < NRANGE / 64; ++nt) {
        const int jBase = nBase + nt * 64;
        float acc[4][4];
        #pragma unroll
        for (int i = 0; i < 4; ++i)
            #pragma unroll
            for (int j = 0; j < 4; ++j) acc[i][j] = 0.f;

        for (int kc = 0; kc < KDIM / 32; ++kc) {
            const int c = kc >> 5, kh = kc & 31;
            const float* xpc = xp + c * (PADW * PADW) + kh * PADW;
            #pragma unroll
            for (int i = 0; i < 8; ++i) {
                int e = i * 256 + t;
                int r = e >> 5, kwi = e & 31;
                int p = rowBase + r;
                float v = 0.f;
                if (p < NP) {
                    int lh = p / LHW, lw = p - lh * LHW;
                    v = xpc[lh * PADW + lw + kwi];
                }
                At[r][kwi] = v;
            }
            const float* mb = mem + (size_t)jBase * KDIM + kc * 32;
            #pragma unroll
            for (int i = 0; i < 8; ++i) {
                int e = i * 256 + t;
                int r = e >> 5, kwi = e & 31;
                Bt[r][kwi] = mb[(size_t)r * KDIM + kwi];
            }
            __syncthreads();
            #pragma unroll
            for (int kk = 0; kk < 32; ++kk) {
                float a[4], b[4];
                #pragma unroll
                for (int i = 0; i < 4; ++i) a[i] = At[ty + 16 * i][kk];
                #pragma unroll
                for (int j = 0; j < 4; ++j) b[j] = Bt[tx + 16 * j][kk];
                #pragma unroll
                for (int i = 0; i < 4; ++i)
                    #pragma unroll
                    for (int j = 0; j < 4; ++j) acc[i][j] += a[i] * b[j];
            }
            __syncthreads();
        }
        #pragma unroll
        for (int j = 0; j < 4; ++j) {
            int col = jBase + tx + 16 * j;
            float msv = msq[col];
            #pragma unroll
            for (int i = 0; i < 4; ++i) {
                float d = msv - 2.f * acc[i][j];
                if (d < best[i] || (d == best[i] && col < bidx[i])) {
                    best[i] = d; bidx[i] = col;
                }
            }
        }
    }
    #pragma unroll
    for (int m = 1; m < 16; m <<= 1) {
        #pragma unroll
        for (int i = 0; i < 4; ++i) {
            float ov = __shfl_xor(best[i], m);
            int   oi = __shfl_xor(bidx[i], m);
            if (ov < best[i] || (ov == best[i] && oi < bidx[i])) {
                best[i] = ov; bidx[i] = oi;
            }
        }
    }
    if (tx == 0) {
        #pragma unroll
        for (int i = 0; i < 4; ++i) {
            int p = rowBase + ty + 16 * i;
            if (p < NP) {
                pval[p * NSPL + blockIdx.y] = best[i];
                pidx[p * NSPL + blockIdx.y] = bidx[i];
            }
        }
    }
}

__global__ __launch_bounds__(256) void k_max(const float* __restrict__ acc,
                                             float* __restrict__ maxv) {
    float m = -BIGF;
    for (int i = threadIdx.x; i < 12288; i += 256) m = fmaxf(m, acc[i]);
    #pragma unroll
    for (int s = 1; s < 64; s <<= 1) m = fmaxf(m, __shfl_xor(m, s));
    __shared__ float ls[4];
    int lane = threadIdx.x & 63, w = threadIdx.x >> 6;
    if (lane == 0) ls[w] = m;
    __syncthreads();
    if (threadIdx.x == 0)
        maxv[0] = fmaxf(fmaxf(ls[0], ls[1]), fmaxf(ls[2], ls[3]));
}

__global__ void k_norm(const float* __restrict__ acc, const float* __restrict__ maxv,
                       float* __restrict__ out) {
    int id = blockIdx.x * 256 + threadIdx.x;
    if (id < 12288) {
        int c = id >> 12, y = (id >> 6) & 63, x = id & 63;
        out[(y * IMG + x) * 3 + c] = acc[id] / maxv[0];
    }
}

// ------------------------------------------------------------------- launch
extern "C" void kernel_launch(void* const* d_in, const int* in_sizes, int n_in,
                              void* d_out, int out_size, void* d_ws, size_t ws_size,
                              hipStream_t stream) {
    const float* image   = (const float*)d_in[0];
    const float* mem     = (const float*)d_in[1];
    const float* mem2    = (const float*)d_in[2];
    const int*   mapping = (const int*)d_in[3];

    if (ws_size >= WS_NEED4) {
        // -------- fast path: i8 screen + sparse candidates + exact refine --
        char* wsB = (char*)d_ws;
        float*    xp    = (float*)(wsB + O_XP);
        float*    msq   = (float*)(wsB + O_MSQ);
        char*     mI8   = (char*)(wsB + O_MI8);
        char*     aI8   = (char*)(wsB + O_AI8);
        float*    candd = (float*)(wsB + O_CANDD);
        int*      candj = (int*)(wsB + O_CANDJ);
        int*      cnt   = (int*)(wsB + O_CNT);
        int*      rowI  = (int*)(wsB + O_ROWI);
        float*    part  = (float*)(wsB + O_PART);
        float*    accb  = (float*)(wsB + O_ACC);

        k_xp<<<dim3((3 * PADW * PADW + 255) / 256), 256, 0, stream>>>(image, xp);
        k_quantmsq<<<dim3(NMEM), 256, 0, stream>>>(mem, mI8, msq);
        k_quant_A<<<dim3(MPAD * KDIM / 4 / 256), 256, 0, stream>>>(xp, aI8, cnt);
        k_gemm_i8<<<dim3(1408), 256, 0, stream>>>(aI8, mI8, msq, candd, candj, cnt);
        k_refine<<<dim3(NP), 256, 0, stream>>>(candd, candj, cnt, msq, xp, mem, mapping, rowI);
        k_scatter<<<dim3(LHW * 3), 256, 0, stream>>>(mem2, rowI, part);
        k_oadd<<<dim3(48), 256, 0, stream>>>(part, accb);
        k_maxnorm<<<dim3(1), 1024, 0, stream>>>(accb, (float*)d_out);
    } else {
        // ---------------- fallback: verified f32 pipeline ----------------
        float* ws   = (float*)d_ws;
        float* xp   = ws + F_XP;
        float* msq  = ws + F_MSQ;
        float* pval = ws + F_PVAL;
        int*   pidx = (int*)(ws + F_PIDX);
        int*   rowI = (int*)(ws + F_ROW);
        float* acc  = ws + F_ACC;
        float* maxv = ws + F_MAX;

        k_xp<<<dim3((3 * PADW * PADW + 255) / 256), 256, 0, stream>>>(image, xp);
        k_msq<<<dim3(NMEM), 256, 0, stream>>>(mem, msq);
        k_gemm_argmin<<<dim3((NP + 63) / 64, NSPL), 256, 0, stream>>>(xp, mem, msq, pval, pidx);
        k_amin<<<dim3((NP + 255) / 256), 256, 0, stream>>>(pval, pidx, mapping, rowI, NSPL);
        k_gather<<<dim3(3 * IMG * IMG), 256, 0, stream>>>(mem2, rowI, acc);
        k_max<<<dim3(1), 256, 0, stream>>>(acc, maxv);
        k_norm<<<dim3((12288 + 255) / 256), 256, 0, stream>>>(acc, maxv, (float*)d_out);
    }
}

// Round 11
// 219.372 us; speedup vs baseline: 1.2073x; 1.2073x over previous
//
#include <hip/hip_runtime.h>

typedef unsigned short u16;
typedef unsigned int   u32;
typedef unsigned long long u64;
typedef int      i32x4  __attribute__((ext_vector_type(4)));
typedef float    f32x4  __attribute__((ext_vector_type(4)));

// Problem constants
#define LHW   53
#define NP    2809
#define KDIM  3072
#define NMEM  8192
#define PADW  84
#define IMG   64
#define MPAD  2816           // 22 * 128 zero-padded patch rows
#define BIGF  3.402823466e+38f
#define MARGIN 24.0f         // i8-screen margin in D units (~17 sigma of pairwise err)
#define QS    31.75f         // i8 scale = 127/4
#define C2    (2.0f / (QS * QS))
#define CAP   12             // candidate slots per (patch, 64-col split)

// ---------------- fast-path ws layout (byte offsets, 256-aligned) ----------
#define O_XP    0UL           // 21168 f32
#define O_MSQ   84736UL       // 8192 f32
#define O_MI8   117504UL      // 8192*3072 i8
#define O_AI8   25283328UL    // 2816*3072 i8
#define O_CAND  33934080UL    // NP*128*CAP u64 (packed d|j)
#define O_CNT   68451072UL    // NP*128 i32
#define O_ROWI  69889280UL    // NP i32
#define O_PART  69900544UL    // 53*3*32*84 f32 partial rows
#define O_ACC   71610112UL    // 12288 f32
#define WS_NEED4 71659264UL

// ---------------- legacy (fallback) ws layout (float-unit offsets) ---------
#define F_XP    0
#define F_MSQ   21504
#define F_PVAL  29696
#define F_PIDX  119584
#define F_ROW   209472
#define F_ACC   212288
#define F_MAX   224576
#define NSPL    32
#define NRANGE  (NMEM / NSPL)

__device__ inline char q8(float x) {
    float y = x * QS;
    y = fminf(fmaxf(y, -127.f), 127.f);
    return (char)__float2int_rn(y);
}

// ============================ shared small kernels ==========================
__global__ void k_xp(const float* __restrict__ image, float* __restrict__ xp) {
    int id = blockIdx.x * 256 + threadIdx.x;
    if (id < 3 * PADW * PADW) {
        int c = id / (PADW * PADW), rem = id % (PADW * PADW);
        int py = rem / PADW, px = rem % PADW;
        float v = 0.f;
        if (py >= 10 && py < 74 && px >= 10 && px < 74)
            v = image[((py - 10) * IMG + (px - 10)) * 3 + c];
        xp[id] = v;
    }
}

// fused max + normalize, single block
__global__ __launch_bounds__(1024) void k_maxnorm(const float* __restrict__ acc,
                                                  float* __restrict__ out) {
    int t = threadIdx.x;
    float m = -BIGF;
    for (int i = t; i < 12288; i += 1024) m = fmaxf(m, acc[i]);
    #pragma unroll
    for (int s = 1; s < 64; s <<= 1) m = fmaxf(m, __shfl_xor(m, s));
    __shared__ float ls[16];
    int lane = t & 63, w = t >> 6;
    if (lane == 0) ls[w] = m;
    __syncthreads();
    float mv = ls[0];
    #pragma unroll
    for (int i = 1; i < 16; ++i) mv = fmaxf(mv, ls[i]);
    for (int i = t; i < 12288; i += 1024) {
        int c = i >> 12, y = (i >> 6) & 63, x = i & 63;
        out[(y * IMG + x) * 3 + c] = acc[i] / mv;
    }
}

// ============================== fast path ===================================
// mem -> i8 plane + exact f32 row sq-norms in one pass
__global__ __launch_bounds__(256) void k_quantmsq(const float* __restrict__ mem,
                                                  char* __restrict__ mq,
                                                  float* __restrict__ msq) {
    int j = blockIdx.x, t = threadIdx.x;
    const float4* r4 = (const float4*)(mem + (size_t)j * KDIM);
    char4* q4 = (char4*)(mq + (size_t)j * KDIM);
    float s = 0.f;
    #pragma unroll
    for (int i = 0; i < 3; ++i) {
        int idx = i * 256 + t;
        float4 v = r4[idx];
        s += v.x * v.x + v.y * v.y + v.z * v.z + v.w * v.w;
        char4 q = {q8(v.x), q8(v.y), q8(v.z), q8(v.w)};
        q4[idx] = q;
    }
    #pragma unroll
    for (int m = 1; m < 64; m <<= 1) s += __shfl_xor(s, m);
    __shared__ float ls[4];
    int lane = t & 63, w = t >> 6;
    if (lane == 0) ls[w] = s;
    __syncthreads();
    if (t == 0) msq[j] = ls[0] + ls[1] + ls[2] + ls[3];
}

// patch matrix (MPAD x KDIM) i8, rows >= NP zero; 4 elems/thread.
// (cnt zeroing no longer needed: GEMM epilogue writes cnt unconditionally.)
__global__ __launch_bounds__(256) void k_quant_A(const float* __restrict__ xp,
                                                 char* __restrict__ aq) {
    int id = blockIdx.x * 256 + threadIdx.x;      // over char4: 2816*3072/4
    int e0 = id * 4;
    int p = e0 / KDIM, k = e0 - p * KDIM;
    char4 q = {0, 0, 0, 0};
    if (p < NP) {
        int c = k >> 10, kh = (k >> 5) & 31, kw = k & 31;
        int lh = p / LHW, lw = p - lh * LHW;
        const float* src = xp + c * (PADW * PADW) + (lh + kh) * PADW + lw + kw;
        q.x = q8(src[0]); q.y = q8(src[1]); q.z = q8(src[2]); q.w = q8(src[3]);
    }
    ((char4*)aq)[id] = q;
}

// i8 screening MFMA GEMM with ATOMIC-FREE in-epilogue candidate collection.
// 128x128 tile, BK=128 (i8), 4 waves of 64x64. Staging: global_load_lds with
// pre-swizzled global source, linear LDS dest (verified rounds 8-10 layout),
// double-buffered. Epilogue (round-10 post-mortem fix): slot indices via
// __ballot + popcount prefix within each 16-lane group -> fire-and-forget
// packed u64 stores, no atomic round-trip dependencies. Each (p, split) is
// owned by exactly one group, so cnt is a plain unconditional store.
__global__ __launch_bounds__(256) void k_gemm_i8(
    const char* __restrict__ Aq, const char* __restrict__ Bq,
    const float* __restrict__ msq, u64* __restrict__ cand,
    int* __restrict__ cnt)
{
    __shared__ __align__(16) char lds[65536];   // buf0/buf1: A @0, B @16384
    const int t = threadIdx.x;
    const int lane = t & 63;
    const int w = t >> 6, wm = w >> 1, wn = w & 1;
    const int mrow = lane & 15;

    // XCD-chunked bijective swizzle: 1408 = 8 * 176
    int L = blockIdx.x;
    int logical = (L & 7) * 176 + (L >> 3);
    int by = logical / 22, bx = logical - by * 22;
    const int rowBase = bx * 128;     // patch rows (A)
    const int jBase   = by * 128;     // mem rows (B)

    // slot s: plane P=s>>2 (A/B), sub=s&3; this wave covers rows sub*32+w*8..+7
    const int lrow = lane >> 3;             // 0..7
    const int gsrc = (lane & 7) ^ lrow;     // pre-swizzled 16B source group
    const char* gpl[8];
    unsigned ldsb[8];
    #pragma unroll
    for (int s = 0; s < 8; ++s) {
        int P = s >> 2, sub = s & 3;
        int row = sub * 32 + w * 8 + lrow;
        const char* basep = (P == 0 ? Aq : Bq);
        int gRow = (P == 0 ? rowBase : jBase) + row;
        gpl[s]  = basep + (size_t)gRow * KDIM + gsrc * 16;
        ldsb[s] = P * 16384 + (unsigned)(sub * 32 + w * 8) * 128;  // +lane*16 by HW
    }

    i32x4 acc[4][4];
    #pragma unroll
    for (int i = 0; i < 4; ++i)
        #pragma unroll
        for (int j = 0; j < 4; ++j) { i32x4 z = {0, 0, 0, 0}; acc[i][j] = z; }

    // prologue: stage k-chunk 0 into buf0
    #pragma unroll
    for (int s = 0; s < 8; ++s)
        __builtin_amdgcn_global_load_lds(
            (const __attribute__((address_space(1))) void*)(gpl[s]),
            (__attribute__((address_space(3))) void*)(lds + ldsb[s]),
            16, 0, 0);

    for (int kc = 0; kc < 24; ++kc) {
        const int cb = kc & 1;
        __syncthreads();                       // vmcnt drain: buf[cb] ready
        if (kc < 23) {
            const unsigned nb = (cb ^ 1) * 32768u;
            #pragma unroll
            for (int s = 0; s < 8; ++s)
                __builtin_amdgcn_global_load_lds(
                    (const __attribute__((address_space(1))) void*)(gpl[s] + (kc + 1) * 128),
                    (__attribute__((address_space(3))) void*)(lds + nb + ldsb[s]),
                    16, 0, 0);
        }
        const char* lbase = lds + cb * 32768;
        #pragma unroll
        for (int kh2 = 0; kh2 < 2; ++kh2) {
            const int grp = kh2 * 4 + (lane >> 4);
            i32x4 ah[4];
            #pragma unroll
            for (int f = 0; f < 4; ++f) {
                int ra = wm * 64 + f * 16 + mrow;
                ah[f] = *(const i32x4*)(lbase + ra * 128 + (grp ^ (ra & 7)) * 16);
            }
            #pragma unroll
            for (int fj = 0; fj < 4; ++fj) {
                int rb = wn * 64 + fj * 16 + mrow;
                i32x4 bh = *(const i32x4*)(lbase + 16384 + rb * 128 + (grp ^ (rb & 7)) * 16);
                #pragma unroll
                for (int fi = 0; fi < 4; ++fi)
                    acc[fi][fj] = __builtin_amdgcn_mfma_i32_16x16x64_i8(ah[fi], bh, acc[fi][fj], 0, 0, 0);
            }
        }
    }

    // epilogue: d = msq[j]-3072 - 2*dot_q/QS^2; ballot-compacted candidate store
    float ms[4];
    #pragma unroll
    for (int fj = 0; fj < 4; ++fj) ms[fj] = msq[jBase + wn * 64 + fj * 16 + mrow] - 3072.0f;
    const int splitId = by * 2 + wn;
    const int g0 = (lane >> 4) * 16;          // group's base lane for ballot window
    #pragma unroll
    for (int fi = 0; fi < 4; ++fi) {
        #pragma unroll
        for (int r = 0; r < 4; ++r) {
            int p = rowBase + wm * 64 + fi * 16 + (lane >> 4) * 4 + r;
            float d4[4]; float bv = BIGF;
            #pragma unroll
            for (int fj = 0; fj < 4; ++fj) {
                d4[fj] = fmaf(-C2, (float)acc[fi][fj][r], ms[fj]);
                bv = fminf(bv, d4[fj]);
            }
            #pragma unroll
            for (int m = 1; m < 16; m <<= 1) bv = fminf(bv, __shfl_xor(bv, m));
            const float th = bv + MARGIN;
            const bool valid = (p < NP);
            const size_t cbase = ((size_t)p * 128 + splitId) * CAP;
            int base = 0;
            #pragma unroll
            for (int fj = 0; fj < 4; ++fj) {
                bool b = valid && (d4[fj] <= th);
                u64 msk = __ballot(b);
                unsigned gm = (unsigned)(msk >> g0) & 0xffffu;
                if (b) {
                    int slot = base + __popc(gm & ((1u << mrow) - 1u));
                    if (slot < CAP) {
                        u64 pk = ((u64)__float_as_uint(d4[fj]) << 32) |
                                 (u32)(jBase + wn * 64 + fj * 16 + mrow);
                        cand[cbase + slot] = pk;   // fire-and-forget
                    }
                }
                base += __popc(gm);
            }
            if (valid && mrow == 0) cnt[(size_t)p * 128 + splitId] = base;
        }
    }
}

// per-patch: global min over stored candidates -> threshold -> exact f32 re-eval
__global__ __launch_bounds__(256) void k_refine(
    const u64* __restrict__ cand, const int* __restrict__ cnt,
    const float* __restrict__ msq, const float* __restrict__ xp,
    const float* __restrict__ mem, const int* __restrict__ mapping,
    int* __restrict__ rowIdx)
{
    const int p = blockIdx.x, t = threadIdx.x;
    const int lane = t & 63, w = t >> 6;
    __shared__ float wred[4];
    __shared__ int lcnt;
    __shared__ int list[256];
    __shared__ float thr_s;

    // this thread's split (t < 128)
    int n = 0;
    if (t < 128) n = min(cnt[(size_t)p * 128 + t], CAP);
    const u64* cp = cand + ((size_t)p * 128 + t) * CAP;

    // pass 1: global min of stored d (every split's min is stored)
    float gm = BIGF;
    for (int i = 0; i < n; ++i)
        gm = fminf(gm, __uint_as_float((u32)(cp[i] >> 32)));
    #pragma unroll
    for (int m = 1; m < 64; m <<= 1) gm = fminf(gm, __shfl_xor(gm, m));
    if (lane == 0) wred[w] = gm;
    if (t == 0) lcnt = 0;
    __syncthreads();
    if (t == 0) thr_s = fminf(fminf(wred[0], wred[1]), fminf(wred[2], wred[3])) + MARGIN;
    __syncthreads();
    const float th = thr_s;

    // pass 2: gather qualifying candidate indices
    for (int i = 0; i < n; ++i) {
        u64 pk = cp[i];
        if (__uint_as_float((u32)(pk >> 32)) <= th) {
            int sl = atomicAdd(&lcnt, 1);
            if (sl < 256) list[sl] = (int)(pk & 0xffffffffu);
        }
    }
    __syncthreads();
    int nc = min(lcnt, 256);

    // pass 3: exact f32 evaluation of each candidate (verified logic)
    const int lh = p / LHW, lw = p - (p / LHW) * LHW;
    float bd = BIGF; int bj = 0x7fffffff;
    __shared__ float tot;
    for (int ci = 0; ci < nc; ++ci) {
        int j = list[ci];
        const float* mrow2 = mem + (size_t)j * KDIM;
        float s = 0.f;
        for (int k = t; k < KDIM; k += 256) {
            int c = k >> 10, kh = (k >> 5) & 31, kw = k & 31;
            s += xp[c * (PADW * PADW) + (lh + kh) * PADW + lw + kw] * mrow2[k];
        }
        #pragma unroll
        for (int m = 1; m < 64; m <<= 1) s += __shfl_xor(s, m);
        if (lane == 0) wred[w] = s;
        __syncthreads();
        if (t == 0) tot = wred[0] + wred[1] + wred[2] + wred[3];
        __syncthreads();
        float d = msq[j] - 2.f * tot;
        if (d < bd || (d == bd && j < bj)) { bd = d; bj = j; }
    }
    if (t == 0) rowIdx[p] = mapping[bj];
}

// -------------------- overlap-add: per-(lh,c) scatter into LDS --------------
// Race-free (verified rounds 5-10): __syncthreads() per lw iteration.
__global__ __launch_bounds__(256) void k_scatter(const float* __restrict__ mem2,
                                                 const int* __restrict__ rowIdx,
                                                 float* __restrict__ partial) {
    const int lh = blockIdx.x / 3, c = blockIdx.x % 3;
    __shared__ float accs[32 * 85];
    __shared__ int r2s[53];
    const int t = threadIdx.x;
    for (int i = t; i < 32 * 85; i += 256) accs[i] = 0.f;
    if (t < 53) r2s[t] = rowIdx[lh * LHW + t];
    __syncthreads();
    const int kh  = t >> 3;            // 0..31 (rows disjoint across threads)
    const int kwb = (t & 7) * 4;       // 0,4,...,28
    const size_t coff = (size_t)c * 1024 + kh * 32 + kwb;
    float* a0 = accs + kh * 85 + kwb;
    for (int lw = 0; lw < 53; ++lw) {
        const float4 v = *(const float4*)(mem2 + (size_t)r2s[lw] * KDIM + coff);
        float* a = a0 + lw;
        a[0] += v.x; a[1] += v.y; a[2] += v.z; a[3] += v.w;
        __syncthreads();               // order iterations: no cross-lw RMW race
    }
    float* pbase = partial + ((size_t)(lh * 3 + c)) * 32 * 84;
    for (int i = t; i < 32 * 84; i += 256) {
        int kh2 = i / 84, px = i - kh2 * 84;
        pbase[i] = accs[kh2 * 85 + px];
    }
}

// per-output-pixel reduce over <=32 kh partial rows
__global__ void k_oadd(const float* __restrict__ partial, float* __restrict__ accb) {
    int id = blockIdx.x * 256 + threadIdx.x;   // 12288
    if (id >= 12288) return;
    int c = id >> 12, y = (id >> 6) & 63, x = id & 63;
    int py = y + 10, px = x + 10;
    int khmin = max(0, py - 52), khmax = min(31, py);
    float s = 0.f;
    for (int kh = khmin; kh <= khmax; ++kh) {
        int lh = py - kh;
        s += partial[((lh * 3 + c) * 32 + kh) * 84 + px];
    }
    accb[id] = s;
}

// ======================= legacy f32 pipeline (fallback) =====================
__global__ __launch_bounds__(256) void k_msq(const float* __restrict__ mem,
                                             float* __restrict__ msq) {
    int j = blockIdx.x;
    const float* row = mem + (size_t)j * KDIM;
    float s = 0.f;
    for (int i = threadIdx.x; i < KDIM; i += 256) { float v = row[i]; s += v * v; }
    #pragma unroll
    for (int m = 1; m < 64; m <<= 1) s += __shfl_xor(s, m);
    __shared__ float ls[4];
    int lane = threadIdx.x & 63, w = threadIdx.x >> 6;
    if (lane == 0) ls[w] = s;
    __syncthreads();
    if (threadIdx.x == 0) msq[j] = ls[0] + ls[1] + ls[2] + ls[3];
}

__global__ void k_amin(const float* __restrict__ pval, const int* __restrict__ pidx,
                       const int* __restrict__ mapping, int* __restrict__ rowIdx,
                       int nspl) {
    int p = blockIdx.x * 256 + threadIdx.x;
    if (p < NP) {
        float bv = BIGF; int bi = 0x7fffffff;
        for (int ns = 0; ns < nspl; ++ns) {
            float v = pval[(size_t)p * nspl + ns];
            int ix = pidx[(size_t)p * nspl + ns];
            if (v < bv || (v == bv && ix < bi)) { bv = v; bi = ix; }
        }
        rowIdx[p] = mapping[bi];
    }
}

__global__ __launch_bounds__(256) void k_gather(const float* __restrict__ mem2,
                                                const int* __restrict__ rowIdx,
                                                float* __restrict__ acc) {
    int b = blockIdx.x;
    int c = b >> 12, y = (b >> 6) & 63, x = b & 63;
    int khmin = max(0, y - 42), khmax = min(31, y + 10);
    int kwmin = max(0, x - 42), kwmax = min(31, x + 10);
    int nh = khmax - khmin + 1, nw = kwmax - kwmin + 1;
    int total = nh * nw;
    float s = 0.f;
    for (int idx = threadIdx.x; idx < total; idx += 256) {
        int kh = khmin + idx / nw;
        int kw = kwmin + idx % nw;
        int lh = y + 10 - kh, lw = x + 10 - kw;
        int p = lh * LHW + lw;
        int r2 = rowIdx[p];
        s += mem2[(size_t)r2 * KDIM + c * 1024 + kh * 32 + kw];
    }
    #pragma unroll
    for (int m = 1; m < 64; m <<= 1) s += __shfl_xor(s, m);
    __shared__ float ls[4];
    int lane = threadIdx.x & 63, w = threadIdx.x >> 6;
    if (lane == 0) ls[w] = s;
    __syncthreads();
    if (threadIdx.x == 0) acc[b] = ls[0] + ls[1] + ls[2] + ls[3];
}

__global__ __launch_bounds__(256) void k_gemm_argmin(
    const float* __restrict__ xp, const float* __restrict__ mem,
    const float* __restrict__ msq, float* __restrict__ pval,
    int* __restrict__ pidx)
{
    __shared__ float At[64][33];
    __shared__ float Bt[64][33];
    const int t = threadIdx.x;
    const int tx = t & 15, ty = t >> 4;
    const int rowBase = blockIdx.x * 64;
    const int nBase = blockIdx.y * NRANGE;

    float best[4]; int bidx[4];
    #pragma unroll
    for (int i = 0; i < 4; ++i) { best[i] = BIGF; bidx[i] = 0x7fffffff; }

    for (int nt = 0; nt < NRANGE / 64; ++nt) {
        const int jBase = nBase + nt * 64;
        float acc[4][4];
        #pragma unroll
        for (int i = 0; i < 4; ++i)
            #pragma unroll
            for (int j = 0; j < 4; ++j) acc[i][j] = 0.f;

        for (int kc = 0; kc < KDIM / 32; ++kc) {
            const int c = kc >> 5, kh = kc & 31;
            const float* xpc = xp + c * (PADW * PADW) + kh * PADW;
            #pragma unroll
            for (int i = 0; i < 8; ++i) {
                int e = i * 256 + t;
                int r = e >> 5, kwi = e & 31;
                int p = rowBase + r;
                float v = 0.f;
                if (p < NP) {
                    int lh = p / LHW, lw = p - lh * LHW;
                    v = xpc[lh * PADW + lw + kwi];
                }
                At[r][kwi] = v;
            }
            const float* mb = mem + (size_t)jBase * KDIM + kc * 32;
            #pragma unroll
            for (int i = 0; i < 8; ++i) {
                int e = i * 256 + t;
                int r = e >> 5, kwi = e & 31;
                Bt[r][kwi] = mb[(size_t)r * KDIM + kwi];
            }
            __syncthreads();
            #pragma unroll
            for (int kk = 0; kk < 32; ++kk) {
                float a[4], b[4];
                #pragma unroll
                for (int i = 0; i < 4; ++i) a[i] = At[ty + 16 * i][kk];
                #pragma unroll
                for (int j = 0; j < 4; ++j) b[j] = Bt[tx + 16 * j][kk];
                #pragma unroll
                for (int i = 0; i < 4; ++i)
                    #pragma unroll
                    for (int j = 0; j < 4; ++j) acc[i][j] += a[i] * b[j];
            }
            __syncthreads();
        }
        #pragma unroll
        for (int j = 0; j < 4; ++j) {
            int col = jBase + tx + 16 * j;
            float msv = msq[col];
            #pragma unroll
            for (int i = 0; i < 4; ++i) {
                float d = msv - 2.f * acc[i][j];
                if (d < best[i] || (d == best[i] && col < bidx[i])) {
                    best[i] = d; bidx[i] = col;
                }
            }
        }
    }
    #pragma unroll
    for (int m = 1; m < 16; m <<= 1) {
        #pragma unroll
        for (int i = 0; i < 4; ++i) {
            float ov = __shfl_xor(best[i], m);
            int   oi = __shfl_xor(bidx[i], m);
            if (ov < best[i] || (ov == best[i] && oi < bidx[i])) {
                best[i] = ov; bidx[i] = oi;
            }
        }
    }
    if (tx == 0) {
        #pragma unroll
        for (int i = 0; i < 4; ++i) {
            int p = rowBase + ty + 16 * i;
            if (p < NP) {
                pval[p * NSPL + blockIdx.y] = best[i];
                pidx[p * NSPL + blockIdx.y] = bidx[i];
            }
        }
    }
}

__global__ __launch_bounds__(256) void k_max(const float* __restrict__ acc,
                                             float* __restrict__ maxv) {
    float m = -BIGF;
    for (int i = threadIdx.x; i < 12288; i += 256) m = fmaxf(m, acc[i]);
    #pragma unroll
    for (int s = 1; s < 64; s <<= 1) m = fmaxf(m, __shfl_xor(m, s));
    __shared__ float ls[4];
    int lane = threadIdx.x & 63, w = threadIdx.x >> 6;
    if (lane == 0) ls[w] = m;
    __syncthreads();
    if (threadIdx.x == 0)
        maxv[0] = fmaxf(fmaxf(ls[0], ls[1]), fmaxf(ls[2], ls[3]));
}

__global__ void k_norm(const float* __restrict__ acc, const float* __restrict__ maxv,
                       float* __restrict__ out) {
    int id = blockIdx.x * 256 + threadIdx.x;
    if (id < 12288) {
        int c = id >> 12, y = (id >> 6) & 63, x = id & 63;
        out[(y * IMG + x) * 3 + c] = acc[id] / maxv[0];
    }
}

// ------------------------------------------------------------------- launch
extern "C" void kernel_launch(void* const* d_in, const int* in_sizes, int n_in,
                              void* d_out, int out_size, void* d_ws, size_t ws_size,
                              hipStream_t stream) {
    const float* image   = (const float*)d_in[0];
    const float* mem     = (const float*)d_in[1];
    const float* mem2    = (const float*)d_in[2];
    const int*   mapping = (const int*)d_in[3];

    if (ws_size >= WS_NEED4) {
        // -------- fast path: i8 screen + ballot candidates + exact refine --
        char* wsB = (char*)d_ws;
        float*    xp    = (float*)(wsB + O_XP);
        float*    msq   = (float*)(wsB + O_MSQ);
        char*     mI8   = (char*)(wsB + O_MI8);
        char*     aI8   = (char*)(wsB + O_AI8);
        u64*      cand  = (u64*)(wsB + O_CAND);
        int*      cnt   = (int*)(wsB + O_CNT);
        int*      rowI  = (int*)(wsB + O_ROWI);
        float*    part  = (float*)(wsB + O_PART);
        float*    accb  = (float*)(wsB + O_ACC);

        k_xp<<<dim3((3 * PADW * PADW + 255) / 256), 256, 0, stream>>>(image, xp);
        k_quantmsq<<<dim3(NMEM), 256, 0, stream>>>(mem, mI8, msq);
        k_quant_A<<<dim3(MPAD * KDIM / 4 / 256), 256, 0, stream>>>(xp, aI8);
        k_gemm_i8<<<dim3(1408), 256, 0, stream>>>(aI8, mI8, msq, cand, cnt);
        k_refine<<<dim3(NP), 256, 0, stream>>>(cand, cnt, msq, xp, mem, mapping, rowI);
        k_scatter<<<dim3(LHW * 3), 256, 0, stream>>>(mem2, rowI, part);
        k_oadd<<<dim3(48), 256, 0, stream>>>(part, accb);
        k_maxnorm<<<dim3(1), 1024, 0, stream>>>(accb, (float*)d_out);
    } else {
        // ---------------- fallback: verified f32 pipeline ----------------
        float* ws   = (float*)d_ws;
        float* xp   = ws + F_XP;
        float* msq  = ws + F_MSQ;
        float* pval = ws + F_PVAL;
        int*   pidx = (int*)(ws + F_PIDX);
        int*   rowI = (int*)(ws + F_ROW);
        float* acc  = ws + F_ACC;
        float* maxv = ws + F_MAX;

        k_xp<<<dim3((3 * PADW * PADW + 255) / 256), 256, 0, stream>>>(image, xp);
        k_msq<<<dim3(NMEM), 256, 0, stream>>>(mem, msq);
        k_gemm_argmin<<<dim3((NP + 63) / 64, NSPL), 256, 0, stream>>>(xp, mem, msq, pval, pidx);
        k_amin<<<dim3((NP + 255) / 256), 256, 0, stream>>>(pval, pidx, mapping, rowI, NSPL);
        k_gather<<<dim3(3 * IMG * IMG), 256, 0, stream>>>(mem2, rowI, acc);
        k_max<<<dim3(1), 256, 0, stream>>>(acc, maxv);
        k_norm<<<dim3((12288 + 255) / 256), 256, 0, stream>>>(acc, maxv, (float*)d_out);
    }
}

// Round 12
// 199.017 us; speedup vs baseline: 1.3308x; 1.1023x over previous
//
#include <hip/hip_runtime.h>

typedef unsigned short u16;
typedef unsigned int   u32;
typedef unsigned long long u64;
typedef int      i32x4  __attribute__((ext_vector_type(4)));
typedef float    f32x4  __attribute__((ext_vector_type(4)));
typedef _Float16 f16x8  __attribute__((ext_vector_type(8)));

// Problem constants
#define LHW   53
#define NP    2809
#define KDIM  3072
#define NMEM  8192
#define PADW  84
#define IMG   64
#define MPAD  2816           // 22 * 128 zero-padded patch rows
#define BIGF  3.402823466e+38f
#define MARGIN 24.0f         // i8-screen margin in D units (~17 sigma of pairwise err)
#define QS    31.75f         // i8 scale = 127/4
#define C2    (2.0f / (QS * QS))

// ---------------- fast-path ws layout (byte offsets, 256-aligned) ----------
#define O_XP    0UL           // 21168 f32
#define O_MSQ   84736UL       // 8192 f32
#define O_MI8   117504UL      // 8192*3072 i8
#define O_AI8   25283328UL    // 2816*3072 i8
#define O_D     33934080UL    // 2816*8192 f16 (D - 3072)
#define O_PVAL  80071424UL    // 2816*128 f32 block-mins
#define O_ROWI  81524480UL    // NP i32
#define O_ACC   81535744UL    // 12288 f32
#define WS_NEED5 81584896UL

// ---------------- legacy (fallback) ws layout (float-unit offsets) ---------
#define F_XP    0
#define F_MSQ   21504
#define F_PVAL  29696
#define F_PIDX  119584
#define F_ROW   209472
#define F_ACC   212288
#define F_MAX   224576
#define NSPL    32
#define NRANGE  (NMEM / NSPL)

__device__ inline char q8(float x) {
    float y = x * QS;
    y = fminf(fmaxf(y, -127.f), 127.f);
    return (char)__float2int_rn(y);
}

// ============================ shared small kernels ==========================
// padded image; also zero-inits the output accumulator (atomic target)
__global__ void k_xp(const float* __restrict__ image, float* __restrict__ xp,
                     float* __restrict__ accb) {
    int id = blockIdx.x * 256 + threadIdx.x;
    if (id < 12288) accb[id] = 0.f;
    if (id < 3 * PADW * PADW) {
        int c = id / (PADW * PADW), rem = id % (PADW * PADW);
        int py = rem / PADW, px = rem % PADW;
        float v = 0.f;
        if (py >= 10 && py < 74 && px >= 10 && px < 74)
            v = image[((py - 10) * IMG + (px - 10)) * 3 + c];
        xp[id] = v;
    }
}

// fused max + normalize, single block
__global__ __launch_bounds__(1024) void k_maxnorm(const float* __restrict__ acc,
                                                  float* __restrict__ out) {
    int t = threadIdx.x;
    float m = -BIGF;
    for (int i = t; i < 12288; i += 1024) m = fmaxf(m, acc[i]);
    #pragma unroll
    for (int s = 1; s < 64; s <<= 1) m = fmaxf(m, __shfl_xor(m, s));
    __shared__ float ls[16];
    int lane = t & 63, w = t >> 6;
    if (lane == 0) ls[w] = m;
    __syncthreads();
    float mv = ls[0];
    #pragma unroll
    for (int i = 1; i < 16; ++i) mv = fmaxf(mv, ls[i]);
    for (int i = t; i < 12288; i += 1024) {
        int c = i >> 12, y = (i >> 6) & 63, x = i & 63;
        out[(y * IMG + x) * 3 + c] = acc[i] / mv;
    }
}

// ============================== fast path ===================================
// mem -> i8 plane + exact f32 row sq-norms in one pass
__global__ __launch_bounds__(256) void k_quantmsq(const float* __restrict__ mem,
                                                  char* __restrict__ mq,
                                                  float* __restrict__ msq) {
    int j = blockIdx.x, t = threadIdx.x;
    const float4* r4 = (const float4*)(mem + (size_t)j * KDIM);
    char4* q4 = (char4*)(mq + (size_t)j * KDIM);
    float s = 0.f;
    #pragma unroll
    for (int i = 0; i < 3; ++i) {
        int idx = i * 256 + t;
        float4 v = r4[idx];
        s += v.x * v.x + v.y * v.y + v.z * v.z + v.w * v.w;
        char4 q = {q8(v.x), q8(v.y), q8(v.z), q8(v.w)};
        q4[idx] = q;
    }
    #pragma unroll
    for (int m = 1; m < 64; m <<= 1) s += __shfl_xor(s, m);
    __shared__ float ls[4];
    int lane = t & 63, w = t >> 6;
    if (lane == 0) ls[w] = s;
    __syncthreads();
    if (t == 0) msq[j] = ls[0] + ls[1] + ls[2] + ls[3];
}

// patch matrix (MPAD x KDIM) i8, rows >= NP zero; 4 elems/thread
__global__ __launch_bounds__(256) void k_quant_A(const float* __restrict__ xp,
                                                 char* __restrict__ aq) {
    int id = blockIdx.x * 256 + threadIdx.x;      // over char4: 2816*3072/4
    int e0 = id * 4;
    int p = e0 / KDIM, k = e0 - p * KDIM;
    char4 q = {0, 0, 0, 0};
    if (p < NP) {
        int c = k >> 10, kh = (k >> 5) & 31, kw = k & 31;
        int lh = p / LHW, lw = p - lh * LHW;
        const float* src = xp + c * (PADW * PADW) + (lh + kh) * PADW + lw + kw;
        q.x = q8(src[0]); q.y = q8(src[1]); q.z = q8(src[2]); q.w = q8(src[3]);
    }
    ((char4*)aq)[id] = q;
}

// i8 screening MFMA GEMM; writes (D' - 3072) as f16 + per-64-col block mins.
// 128x128 tile, BK=128 (i8), 4 waves of 64x64. Staging: global_load_lds with
// pre-swizzled global source, linear LDS dest (verified rounds 8-9 layout),
// double-buffered. Epilogue: r9-verified (f16 Dm burst stores are hidden;
// r10/r11 showed in-epilogue candidate collection regresses).
__global__ __launch_bounds__(256) void k_gemm_i8(
    const char* __restrict__ Aq, const char* __restrict__ Bq,
    const float* __restrict__ msq, _Float16* __restrict__ Dm,
    float* __restrict__ pval)
{
    __shared__ __align__(16) char lds[65536];   // buf0/buf1: A @0, B @16384
    const int t = threadIdx.x;
    const int lane = t & 63;
    const int w = t >> 6, wm = w >> 1, wn = w & 1;
    const int mrow = lane & 15;

    // XCD-chunked bijective swizzle: 1408 = 8 * 176
    int L = blockIdx.x;
    int logical = (L & 7) * 176 + (L >> 3);
    int by = logical / 22, bx = logical - by * 22;
    const int rowBase = bx * 128;     // patch rows (A)
    const int jBase   = by * 128;     // mem rows (B)

    // slot s: plane P=s>>2 (A/B), sub=s&3; this wave covers rows sub*32+w*8..+7
    const int lrow = lane >> 3;             // 0..7
    const int gsrc = (lane & 7) ^ lrow;     // pre-swizzled 16B source group
    const char* gpl[8];
    unsigned ldsb[8];
    #pragma unroll
    for (int s = 0; s < 8; ++s) {
        int P = s >> 2, sub = s & 3;
        int row = sub * 32 + w * 8 + lrow;
        const char* basep = (P == 0 ? Aq : Bq);
        int gRow = (P == 0 ? rowBase : jBase) + row;
        gpl[s]  = basep + (size_t)gRow * KDIM + gsrc * 16;
        ldsb[s] = P * 16384 + (unsigned)(sub * 32 + w * 8) * 128;  // +lane*16 by HW
    }

    i32x4 acc[4][4];
    #pragma unroll
    for (int i = 0; i < 4; ++i)
        #pragma unroll
        for (int j = 0; j < 4; ++j) { i32x4 z = {0, 0, 0, 0}; acc[i][j] = z; }

    // prologue: stage k-chunk 0 into buf0
    #pragma unroll
    for (int s = 0; s < 8; ++s)
        __builtin_amdgcn_global_load_lds(
            (const __attribute__((address_space(1))) void*)(gpl[s]),
            (__attribute__((address_space(3))) void*)(lds + ldsb[s]),
            16, 0, 0);

    for (int kc = 0; kc < 24; ++kc) {
        const int cb = kc & 1;
        __syncthreads();                       // vmcnt drain: buf[cb] ready
        if (kc < 23) {
            const unsigned nb = (cb ^ 1) * 32768u;
            #pragma unroll
            for (int s = 0; s < 8; ++s)
                __builtin_amdgcn_global_load_lds(
                    (const __attribute__((address_space(1))) void*)(gpl[s] + (kc + 1) * 128),
                    (__attribute__((address_space(3))) void*)(lds + nb + ldsb[s]),
                    16, 0, 0);
        }
        const char* lbase = lds + cb * 32768;
        #pragma unroll
        for (int kh2 = 0; kh2 < 2; ++kh2) {
            const int grp = kh2 * 4 + (lane >> 4);
            i32x4 ah[4];
            #pragma unroll
            for (int f = 0; f < 4; ++f) {
                int ra = wm * 64 + f * 16 + mrow;
                ah[f] = *(const i32x4*)(lbase + ra * 128 + (grp ^ (ra & 7)) * 16);
            }
            #pragma unroll
            for (int fj = 0; fj < 4; ++fj) {
                int rb = wn * 64 + fj * 16 + mrow;
                i32x4 bh = *(const i32x4*)(lbase + 16384 + rb * 128 + (grp ^ (rb & 7)) * 16);
                #pragma unroll
                for (int fi = 0; fi < 4; ++fi)
                    acc[fi][fj] = __builtin_amdgcn_mfma_i32_16x16x64_i8(ah[fi], bh, acc[fi][fj], 0, 0, 0);
            }
        }
    }

    // epilogue: D' = msq[j]-3072 - 2*dot_q/QS^2 -> f16 store + 64-col block min
    float ms[4];
    #pragma unroll
    for (int fj = 0; fj < 4; ++fj) ms[fj] = msq[jBase + wn * 64 + fj * 16 + mrow] - 3072.0f;
    const int splitId = by * 2 + wn;
    #pragma unroll
    for (int fi = 0; fi < 4; ++fi) {
        #pragma unroll
        for (int r = 0; r < 4; ++r) {
            int p = rowBase + wm * 64 + fi * 16 + (lane >> 4) * 4 + r;
            float bv = BIGF;
            #pragma unroll
            for (int fj = 0; fj < 4; ++fj) {
                int j = jBase + wn * 64 + fj * 16 + mrow;
                float d = fmaf(-C2, (float)acc[fi][fj][r], ms[fj]);
                Dm[(size_t)p * NMEM + j] = (_Float16)d;
                bv = fminf(bv, d);
            }
            #pragma unroll
            for (int m = 1; m < 16; m <<= 1) bv = fminf(bv, __shfl_xor(bv, m));
            if (mrow == 0 && p < NP)
                pval[(size_t)p * 128 + splitId] = bv;
        }
    }
}

// per-patch: in-block threshold from the 128 block-mins, single Dm scan for
// candidates, exact f32 re-eval (verified logic; k_thr fused in)
__global__ __launch_bounds__(256) void k_refine(
    const _Float16* __restrict__ Dm, const float* __restrict__ pval,
    const float* __restrict__ msq, const float* __restrict__ xp,
    const float* __restrict__ mem, const int* __restrict__ mapping,
    int* __restrict__ rowIdx)
{
    const int p = blockIdx.x, t = threadIdx.x;
    const _Float16* row = Dm + (size_t)p * NMEM;
    const int lane = t & 63, w = t >> 6;

    __shared__ float wred[4];
    __shared__ int lcnt;
    __shared__ int list[256];
    __shared__ float thr_s;

    // fused k_thr: min over the 128 split-mins (+0.5 guards Dm's f16 rounding)
    float pm = (t < 128) ? pval[(size_t)p * 128 + t] : BIGF;
    #pragma unroll
    for (int m = 1; m < 64; m <<= 1) pm = fminf(pm, __shfl_xor(pm, m));
    if (lane == 0) wred[w] = pm;
    if (t == 0) lcnt = 0;
    __syncthreads();
    if (t == 0)
        thr_s = fminf(fminf(wred[0], wred[1]), fminf(wred[2], wred[3]))
                + (MARGIN + 0.5f);
    __syncthreads();
    const float th = thr_s;

    // collect candidates (single Dm scan)
    #pragma unroll
    for (int i0 = 0; i0 < 4; ++i0) {
        int base = i0 * 2048 + t * 8;
        f16x8 v = *(const f16x8*)(row + base);
        #pragma unroll
        for (int e = 0; e < 8; ++e)
            if ((float)v[e] <= th) {
                int sl = atomicAdd(&lcnt, 1);
                if (sl < 256) list[sl] = base + e;
            }
    }
    __syncthreads();
    int nc = min(lcnt, 256);

    // exact f32 evaluation of each candidate
    const int lh = p / LHW, lw = p - (p / LHW) * LHW;
    float bd = BIGF; int bj = 0x7fffffff;
    __shared__ float tot;
    for (int ci = 0; ci < nc; ++ci) {
        int j = list[ci];
        const float* mrow2 = mem + (size_t)j * KDIM;
        float s = 0.f;
        for (int k = t; k < KDIM; k += 256) {
            int c = k >> 10, kh = (k >> 5) & 31, kw = k & 31;
            s += xp[c * (PADW * PADW) + (lh + kh) * PADW + lw + kw] * mrow2[k];
        }
        #pragma unroll
        for (int m = 1; m < 64; m <<= 1) s += __shfl_xor(s, m);
        if (lane == 0) wred[w] = s;
        __syncthreads();
        if (t == 0) tot = wred[0] + wred[1] + wred[2] + wred[3];
        __syncthreads();
        float d = msq[j] - 2.f * tot;
        if (d < bd || (d == bd && j < bj)) { bd = d; bj = j; }
    }
    if (t == 0) rowIdx[p] = mapping[bj];
}

// -------------------- overlap-add: per-(lh,c) scatter into LDS --------------
// Race-free accumulation (verified rounds 5-11): __syncthreads() per lw
// iteration. Write-out now adds directly into accb with the crop bounds
// (replaces partial buffer + k_oadd). accb zero-init'd by k_xp each call.
__global__ __launch_bounds__(256) void k_scatter(const float* __restrict__ mem2,
                                                 const int* __restrict__ rowIdx,
                                                 float* __restrict__ accb) {
    const int lh = blockIdx.x / 3, c = blockIdx.x % 3;
    __shared__ float accs[32 * 85];
    __shared__ int r2s[53];
    const int t = threadIdx.x;
    for (int i = t; i < 32 * 85; i += 256) accs[i] = 0.f;
    if (t < 53) r2s[t] = rowIdx[lh * LHW + t];
    __syncthreads();
    const int kh  = t >> 3;            // 0..31 (rows disjoint across threads)
    const int kwb = (t & 7) * 4;       // 0,4,...,28
    const size_t coff = (size_t)c * 1024 + kh * 32 + kwb;
    float* a0 = accs + kh * 85 + kwb;
    for (int lw = 0; lw < 53; ++lw) {
        const float4 v = *(const float4*)(mem2 + (size_t)r2s[lw] * KDIM + coff);
        float* a = a0 + lw;
        a[0] += v.x; a[1] += v.y; a[2] += v.z; a[3] += v.w;
        __syncthreads();               // order iterations: no cross-lw RMW race
    }
    // write-out: padded (py=lh+kh, px) -> cropped (y, x), atomic overlap-add
    for (int i = t; i < 32 * 84; i += 256) {
        int kh2 = i / 84, px = i - kh2 * 84;
        int y = lh + kh2 - 10, x = px - 10;
        if (y >= 0 && y < 64 && x >= 0 && x < 64)
            atomicAdd(&accb[c * 4096 + y * 64 + x], accs[kh2 * 85 + px]);
    }
}

// ======================= legacy f32 pipeline (fallback) =====================
__global__ __launch_bounds__(256) void k_msq(const float* __restrict__ mem,
                                             float* __restrict__ msq) {
    int j = blockIdx.x;
    const float* row = mem + (size_t)j * KDIM;
    float s = 0.f;
    for (int i = threadIdx.x; i < KDIM; i += 256) { float v = row[i]; s += v * v; }
    #pragma unroll
    for (int m = 1; m < 64; m <<= 1) s += __shfl_xor(s, m);
    __shared__ float ls[4];
    int lane = threadIdx.x & 63, w = threadIdx.x >> 6;
    if (lane == 0) ls[w] = s;
    __syncthreads();
    if (threadIdx.x == 0) msq[j] = ls[0] + ls[1] + ls[2] + ls[3];
}

__global__ void k_amin(const float* __restrict__ pval, const int* __restrict__ pidx,
                       const int* __restrict__ mapping, int* __restrict__ rowIdx,
                       int nspl) {
    int p = blockIdx.x * 256 + threadIdx.x;
    if (p < NP) {
        float bv = BIGF; int bi = 0x7fffffff;
        for (int ns = 0; ns < nspl; ++ns) {
            float v = pval[(size_t)p * nspl + ns];
            int ix = pidx[(size_t)p * nspl + ns];
            if (v < bv || (v == bv && ix < bi)) { bv = v; bi = ix; }
        }
        rowIdx[p] = mapping[bi];
    }
}

__global__ __launch_bounds__(256) void k_gather(const float* __restrict__ mem2,
                                                const int* __restrict__ rowIdx,
                                                float* __restrict__ acc) {
    int b = blockIdx.x;
    int c = b >> 12, y = (b >> 6) & 63, x = b & 63;
    int khmin = max(0, y - 42), khmax = min(31, y + 10);
    int kwmin = max(0, x - 42), kwmax = min(31, x + 10);
    int nh = khmax - khmin + 1, nw = kwmax - kwmin + 1;
    int total = nh * nw;
    float s = 0.f;
    for (int idx = threadIdx.x; idx < total; idx += 256) {
        int kh = khmin + idx / nw;
        int kw = kwmin + idx % nw;
        int lh = y + 10 - kh, lw = x + 10 - kw;
        int p = lh * LHW + lw;
        int r2 = rowIdx[p];
        s += mem2[(size_t)r2 * KDIM + c * 1024 + kh * 32 + kw];
    }
    #pragma unroll
    for (int m = 1; m < 64; m <<= 1) s += __shfl_xor(s, m);
    __shared__ float ls[4];
    int lane = threadIdx.x & 63, w = threadIdx.x >> 6;
    if (lane == 0) ls[w] = s;
    __syncthreads();
    if (threadIdx.x == 0) acc[b] = ls[0] + ls[1] + ls[2] + ls[3];
}

__global__ __launch_bounds__(256) void k_gemm_argmin(
    const float* __restrict__ xp, const float* __restrict__ mem,
    const float* __restrict__ msq, float* __restrict__ pval,
    int* __restrict__ pidx)
{
    __shared__ float At[64][33];
    __shared__ float Bt[64][33];
    const int t = threadIdx.x;
    const int tx = t & 15, ty = t >> 4;
    const int rowBase = blockIdx.x * 64;
    const int nBase = blockIdx.y * NRANGE;

    float best[4]; int bidx[4];
    #pragma unroll
    for (int i = 0; i < 4; ++i) { best[i] = BIGF; bidx[i] = 0x7fffffff; }

    for (int nt = 0; nt < NRANGE / 64; ++nt) {
        const int jBase = nBase + nt * 64;
        float acc[4][4];
        #pragma unroll
        for (int i = 0; i < 4; ++i)
            #pragma unroll
            for (int j = 0; j < 4; ++j) acc[i][j] = 0.f;

        for (int kc = 0; kc < KDIM / 32; ++kc) {
            const int c = kc >> 5, kh = kc & 31;
            const float* xpc = xp + c * (PADW * PADW) + kh * PADW;
            #pragma unroll
            for (int i = 0; i < 8; ++i) {
                int e = i * 256 + t;
                int r = e >> 5, kwi = e & 31;
                int p = rowBase + r;
                float v = 0.f;
                if (p < NP) {
                    int lh = p / LHW, lw = p - lh * LHW;
                    v = xpc[lh * PADW + lw + kwi];
                }
                At[r][kwi] = v;
            }
            const float* mb = mem + (size_t)jBase * KDIM + kc * 32;
            #pragma unroll
            for (int i = 0; i < 8; ++i) {
                int e = i * 256 + t;
                int r = e >> 5, kwi = e & 31;
                Bt[r][kwi] = mb[(size_t)r * KDIM + kwi];
            }
            __syncthreads();
            #pragma unroll
            for (int kk = 0; kk < 32; ++kk) {
                float a[4], b[4];
                #pragma unroll
                for (int i = 0; i < 4; ++i) a[i] = At[ty + 16 * i][kk];
                #pragma unroll
                for (int j = 0; j < 4; ++j) b[j] = Bt[tx + 16 * j][kk];
                #pragma unroll
                for (int i = 0; i < 4; ++i)
                    #pragma unroll
                    for (int j = 0; j < 4; ++j) acc[i][j] += a[i] * b[j];
            }
            __syncthreads();
        }
        #pragma unroll
        for (int j = 0; j < 4; ++j) {
            int col = jBase + tx + 16 * j;
            float msv = msq[col];
            #pragma unroll
            for (int i = 0; i < 4; ++i) {
                float d = msv - 2.f * acc[i][j];
                if (d < best[i] || (d == best[i] && col < bidx[i])) {
                    best[i] = d; bidx[i] = col;
                }
            }
        }
    }
    #pragma unroll
    for (int m = 1; m < 16; m <<= 1) {
        #pragma unroll
        for (int i = 0; i < 4; ++i) {
            float ov = __shfl_xor(best[i], m);
            int   oi = __shfl_xor(bidx[i], m);
            if (ov < best[i] || (ov == best[i] && oi < bidx[i])) {
                best[i] = ov; bidx[i] = oi;
            }
        }
    }
    if (tx == 0) {
        #pragma unroll
        for (int i = 0; i < 4; ++i) {
            int p = rowBase + ty + 16 * i;
            if (p < NP) {
                pval[p * NSPL + blockIdx.y] = best[i];
                pidx[p * NSPL + blockIdx.y] = bidx[i];
            }
        }
    }
}

__global__ __launch_bounds__(256) void k_max(const float* __restrict__ acc,
                                             float* __restrict__ maxv) {
    float m = -BIGF;
    for (int i = threadIdx.x; i < 12288; i += 256) m = fmaxf(m, acc[i]);
    #pragma unroll
    for (int s = 1; s < 64; s <<= 1) m = fmaxf(m, __shfl_xor(m, s));
    __shared__ float ls[4];
    int lane = threadIdx.x & 63, w = threadIdx.x >> 6;
    if (lane == 0) ls[w] = m;
    __syncthreads();
    if (threadIdx.x == 0)
        maxv[0] = fmaxf(fmaxf(ls[0], ls[1]), fmaxf(ls[2], ls[3]));
}

__global__ void k_norm(const float* __restrict__ acc, const float* __restrict__ maxv,
                       float* __restrict__ out) {
    int id = blockIdx.x * 256 + threadIdx.x;
    if (id < 12288) {
        int c = id >> 12, y = (id >> 6) & 63, x = id & 63;
        out[(y * IMG + x) * 3 + c] = acc[id] / maxv[0];
    }
}

// ------------------------------------------------------------------- launch
extern "C" void kernel_launch(void* const* d_in, const int* in_sizes, int n_in,
                              void* d_out, int out_size, void* d_ws, size_t ws_size,
                              hipStream_t stream) {
    const float* image   = (const float*)d_in[0];
    const float* mem     = (const float*)d_in[1];
    const float* mem2    = (const float*)d_in[2];
    const int*   mapping = (const int*)d_in[3];

    if (ws_size >= WS_NEED5) {
        // ---- fast path: i8 screen (r9 GEMM) + fused refine + atomic OA ----
        char* wsB = (char*)d_ws;
        float*    xp   = (float*)(wsB + O_XP);
        float*    msq  = (float*)(wsB + O_MSQ);
        char*     mI8  = (char*)(wsB + O_MI8);
        char*     aI8  = (char*)(wsB + O_AI8);
        _Float16* Dm   = (_Float16*)(wsB + O_D);
        float*    pval = (float*)(wsB + O_PVAL);
        int*      rowI = (int*)(wsB + O_ROWI);
        float*    accb = (float*)(wsB + O_ACC);

        k_xp<<<dim3((3 * PADW * PADW + 255) / 256), 256, 0, stream>>>(image, xp, accb);
        k_quantmsq<<<dim3(NMEM), 256, 0, stream>>>(mem, mI8, msq);
        k_quant_A<<<dim3(MPAD * KDIM / 4 / 256), 256, 0, stream>>>(xp, aI8);
        k_gemm_i8<<<dim3(1408), 256, 0, stream>>>(aI8, mI8, msq, Dm, pval);
        k_refine<<<dim3(NP), 256, 0, stream>>>(Dm, pval, msq, xp, mem, mapping, rowI);
        k_scatter<<<dim3(LHW * 3), 256, 0, stream>>>(mem2, rowI, accb);
        k_maxnorm<<<dim3(1), 1024, 0, stream>>>(accb, (float*)d_out);
    } else {
        // ---------------- fallback: verified f32 pipeline ----------------
        float* ws   = (float*)d_ws;
        float* xp   = ws + F_XP;
        float* msq  = ws + F_MSQ;
        float* pval = ws + F_PVAL;
        int*   pidx = (int*)(ws + F_PIDX);
        int*   rowI = (int*)(ws + F_ROW);
        float* acc  = ws + F_ACC;
        float* maxv = ws + F_MAX;

        k_xp<<<dim3((3 * PADW * PADW + 255) / 256), 256, 0, stream>>>(image, xp, acc);
        k_msq<<<dim3(NMEM), 256, 0, stream>>>(mem, msq);
        k_gemm_argmin<<<dim3((NP + 63) / 64, NSPL), 256, 0, stream>>>(xp, mem, msq, pval, pidx);
        k_amin<<<dim3((NP + 255) / 256), 256, 0, stream>>>(pval, pidx, mapping, rowI, NSPL);
        k_gather<<<dim3(3 * IMG * IMG), 256, 0, stream>>>(mem2, rowI, acc);
        k_max<<<dim3(1), 256, 0, stream>>>(acc, maxv);
        k_norm<<<dim3((12288 + 255) / 256), 256, 0, stream>>>(acc, maxv, (float*)d_out);
    }
}